// Round 4
// baseline (115.454 us; speedup 1.0000x reference)
//
#include <hip/hip_runtime.h>
#include <math.h>

#define NQ 8
#define NDEPTH 3
#define FEAT 512
#define NCLS 10
#define NBATCH 8192

typedef _Float16 v8h __attribute__((ext_vector_type(8)));
typedef float v4f __attribute__((ext_vector_type(4)));

// ---------------------------------------------------------------------------
// Workspace layout:
//   T:   256*10 f32 @ 0       (10240 B)
//   PB:  16*512 f16 @ 16384   (16384 B)  proj_w rows 0..7, zero-padded 8..15
//   Bre: 256*256 f16 @ 32768  (131072 B) circuit unitary, MFMA-B packed
//   Bim: 256*256 f16 @ 163840 (131072 B)
// ---------------------------------------------------------------------------

// ---------------------------------------------------------------------------
// DPP helpers (HW-verified R2/R3)
// ---------------------------------------------------------------------------
template <int CTRL, int ROW_MASK>
__device__ __forceinline__ float dpp_term(float v) {
    return __int_as_float(__builtin_amdgcn_update_dpp(
        0, __float_as_int(v), CTRL, ROW_MASK, 0xf, true));
}

template <int CTRL>
__device__ __forceinline__ float dpp_xor(float v) {
    return __int_as_float(__builtin_amdgcn_update_dpp(
        0, __float_as_int(v), CTRL, 0xf, 0xf, true));
}

__device__ __forceinline__ float fast_tanh(float v) {
    float e = __expf(2.f * v);
    return 1.f - 2.f / (e + 1.f);
}

// ---------------------------------------------------------------------------
// Gate application (HW-verified R2/R3). State: amp index = lane*4 + j.
// ---------------------------------------------------------------------------
__device__ __forceinline__ void cgate_pair(const float* __restrict__ u,
        float& r0, float& i0, float& r1, float& i1) {
    float nr0 = u[0]*r0 - u[1]*i0 + u[2]*r1 - u[3]*i1;
    float ni0 = u[0]*i0 + u[1]*r0 + u[2]*i1 + u[3]*r1;
    float nr1 = u[4]*r0 - u[5]*i0 + u[6]*r1 - u[7]*i1;
    float ni1 = u[4]*i0 + u[5]*r0 + u[6]*i1 + u[7]*r1;
    r0 = nr0; i0 = ni0; r1 = nr1; i1 = ni1;
}

__device__ __forceinline__ void cgate_shfl(const float* __restrict__ u, int bit,
        int mask, float (&re)[4], float (&im)[4]) {
    float dr  = bit ? u[6] : u[0], di = bit ? u[7] : u[1];
    float orr = bit ? u[4] : u[2], oi = bit ? u[5] : u[3];
#pragma unroll
    for (int j = 0; j < 4; j++) {
        float pr = __shfl_xor(re[j], mask);
        float pi = __shfl_xor(im[j], mask);
        float nr = dr*re[j] - di*im[j] + orr*pr - oi*pi;
        float ni = dr*im[j] + di*re[j] + orr*pi + oi*pr;
        re[j] = nr; im[j] = ni;
    }
}

template <int CTRL>
__device__ __forceinline__ void cgate_dpp(const float* __restrict__ u, int bit,
        float (&re)[4], float (&im)[4]) {
    float dr  = bit ? u[6] : u[0], di = bit ? u[7] : u[1];
    float orr = bit ? u[4] : u[2], oi = bit ? u[5] : u[3];
#pragma unroll
    for (int j = 0; j < 4; j++) {
        float pr = dpp_xor<CTRL>(re[j]);
        float pi = dpp_xor<CTRL>(im[j]);
        float nr = dr*re[j] - di*im[j] + orr*pr - oi*pi;
        float ni = dr*im[j] + di*re[j] + orr*pi + oi*pr;
        re[j] = nr; im[j] = ni;
    }
}

__device__ __forceinline__ void apply_circuit(const float* __restrict__ gates,
        int lane, float (&re)[4], float (&im)[4]) {
#pragma unroll
    for (int l = 0; l < NDEPTH; l++) {
        const float* g = gates + l * NQ * 8;
        cgate_pair(g, re[0], im[0], re[1], im[1]);
        cgate_pair(g, re[2], im[2], re[3], im[3]);
        cgate_pair(g + 8,  re[0], im[0], re[2], im[2]);
        cgate_pair(g + 8,  re[1], im[1], re[3], im[3]);
        cgate_dpp<0xB1>(g + 16, lane & 1,        re, im);
        cgate_dpp<0x4E>(g + 24, (lane >> 1) & 1, re, im);
        cgate_shfl(g + 32, (lane >> 2) & 1, 4,  re, im);
        cgate_shfl(g + 40, (lane >> 3) & 1, 8,  re, im);
        cgate_shfl(g + 48, (lane >> 4) & 1, 16, re, im);
        cgate_shfl(g + 56, (lane >> 5) & 1, 32, re, im);
        { float t = re[1]; re[1] = re[3]; re[3] = t;
          t = im[1]; im[1] = im[3]; im[3] = t; }
        int base  = lane ^ ((lane << 1) & 63);
        int base2 = base ^ 1;
        re[0] = __shfl(re[0], base);  im[0] = __shfl(im[0], base);
        re[1] = __shfl(re[1], base);  im[1] = __shfl(im[1], base);
        re[2] = __shfl(re[2], base2); im[2] = __shfl(im[2], base2);
        re[3] = __shfl(re[3], base2); im[3] = __shfl(im[3], base2);
        int bit5 = (lane >> 5) & 1;
        {
            float t0 = bit5 ? re[1] : re[0], t1 = bit5 ? re[0] : re[1];
            float t2 = bit5 ? re[3] : re[2], t3 = bit5 ? re[2] : re[3];
            re[0] = t0; re[1] = t1; re[2] = t2; re[3] = t3;
            t0 = bit5 ? im[1] : im[0]; t1 = bit5 ? im[0] : im[1];
            t2 = bit5 ? im[3] : im[2]; t3 = bit5 ? im[2] : im[3];
            im[0] = t0; im[1] = t1; im[2] = t2; im[3] = t3;
        }
    }
}

// ---------------------------------------------------------------------------
// k1: one block per basis column p. Gates computed per-block into LDS;
// block 0 additionally writes T and the f16-padded proj_w (PB).
// ---------------------------------------------------------------------------
__global__ __launch_bounds__(64) void build_all(
        const float* __restrict__ qnn_w, const float* __restrict__ proj_w,
        const float* __restrict__ out_w,
        float* __restrict__ T, _Float16* __restrict__ PB,
        _Float16* __restrict__ Bre, _Float16* __restrict__ Bim) {
    __shared__ float gl[NDEPTH * NQ * 8];
    int tid = threadIdx.x;
    if (tid < NDEPTH * NQ) {
        float t0 = 0.5f * qnn_w[tid * 3 + 0];
        float t1 = 0.5f * qnn_w[tid * 3 + 1];
        float t2 = 0.5f * qnn_w[tid * 3 + 2];
        float c0 = cosf(t0), s0 = sinf(t0);
        float c1 = cosf(t1), s1 = sinf(t1);
        float c2 = cosf(t2), s2 = sinf(t2);
        float m00r =  c1 * c0, m00i =  s1 * s0;
        float m01r = -s1 * c0, m01i = -c1 * s0;
        float m10r =  s1 * c0, m10i = -c1 * s0;
        float m11r =  c1 * c0, m11i = -s1 * s0;
        float* g = gl + tid * 8;
        g[0] =  c2 * m00r + s2 * m10i;  g[1] =  c2 * m00i - s2 * m10r;
        g[2] =  c2 * m01r + s2 * m11i;  g[3] =  c2 * m01i - s2 * m11r;
        g[4] =  s2 * m00i + c2 * m10r;  g[5] = -s2 * m00r + c2 * m10i;
        g[6] =  s2 * m01i + c2 * m11r;  g[7] = -s2 * m01r + c2 * m11i;
    }
    if (blockIdx.x == 0) {
        // T[i][c] = sum_q (1 - 2*bit_q(i)) * out_w[c][q]
        for (int i = tid; i < 256; i += 64) {
#pragma unroll
            for (int c = 0; c < NCLS; c++) {
                float s = 0.f;
#pragma unroll
                for (int q = 0; q < NQ; q++)
                    s += (((i >> q) & 1) ? -1.f : 1.f) * out_w[c * NQ + q];
                T[i * NCLS + c] = s;
            }
        }
        // PB[n][k]: f16 proj_w for n<8, zeros for 8<=n<16 (MFMA N padding)
        for (int e = 0; e < 128; e++) {
            int idx = e * 64 + tid;
            int n = idx >> 9, k = idx & 511;
            PB[idx] = (n < 8) ? (_Float16)proj_w[n * FEAT + k] : (_Float16)0.f;
        }
    }
    __syncthreads();

    int lane = tid; // 1 wave per block
    int p = blockIdx.x;
    float re[4], im[4];
#pragma unroll
    for (int j = 0; j < 4; j++) {
        re[j] = (lane * 4 + j == p) ? 1.f : 0.f;
        im[j] = 0.f;
    }
    apply_circuit(gl, lane, re, im);

    // scatter into MFMA-B fragment layout (HW-verified R3)
    int t  = lane >> 2;
    int kk = p >> 5;
    int qp = (p >> 3) & 3;
    int j  = p & 7;
#pragma unroll
    for (int r = 0; r < 4; r++) {
        int n15  = (lane & 3) * 4 + r;
        int flat = ((t * 8 + kk) * 64 + qp * 16 + n15) * 8 + j;
        Bre[flat] = (_Float16)re[r];
        Bim[flat] = (_Float16)im[r];
    }
}

// ---------------------------------------------------------------------------
// k2: fused encoding-dots (MFMA) + product-state build + PSI GEMM + head.
// 256 blocks x 128 threads; each wave handles 16 batch rows.
// ---------------------------------------------------------------------------
__global__ __launch_bounds__(128) void enc_gemm_head(
        const float* __restrict__ x, const _Float16* __restrict__ PB,
        const _Float16* __restrict__ Bre, const _Float16* __restrict__ Bim,
        const float* __restrict__ T, const float* __restrict__ out_b,
        float* __restrict__ out) {
    __shared__ float Tl[256 * NCLS];
    __shared__ float cs[2][16][16]; // [wave][row][q*2 + (0=c,1=s)]

    int tid = threadIdx.x;
    for (int e = 0; e < 20; e++) Tl[e * 128 + tid] = T[e * 128 + tid];
    __syncthreads();

    int lane = tid & 63;
    int gw   = tid >> 6;
    int m    = lane & 15, quad = lane >> 4;
    int rowbase = (blockIdx.x * 2 + gw) * 16;

    // ---- encoding dots via MFMA: D[row][q] = x[row]·proj_w[q] -------------
    const float* xrow = x + (size_t)(rowbase + m) * FEAT;
    v4f dacc = {0.f, 0.f, 0.f, 0.f};
#pragma unroll
    for (int kk = 0; kk < 16; kk++) {
        int k0 = kk * 32 + quad * 8;
        float4 xa = *(const float4*)(xrow + k0);
        float4 xb = *(const float4*)(xrow + k0 + 4);
        v8h av;
        av[0] = (_Float16)xa.x; av[1] = (_Float16)xa.y;
        av[2] = (_Float16)xa.z; av[3] = (_Float16)xa.w;
        av[4] = (_Float16)xb.x; av[5] = (_Float16)xb.y;
        av[6] = (_Float16)xb.z; av[7] = (_Float16)xb.w;
        v8h bv = *(const v8h*)(PB + m * FEAT + k0);
        dacc = __builtin_amdgcn_mfma_f32_16x16x32_f16(av, bv, dacc, 0, 0, 0);
    }
    // lane holds D[row = rowbase+quad*4+r][q = m] (C-layout, verified m89)
#pragma unroll
    for (int r = 0; r < 4; r++) {
        float th = fast_tanh(dacc[r]) * 0.78539816339744830962f; // half-angle
        float sv = __sinf(th), cv = __cosf(th);
        if (m < 8) {
            cs[gw][quad * 4 + r][m * 2]     = cv;
            cs[gw][quad * 4 + r][m * 2 + 1] = sv;
        }
    }
    // wave-local LDS: same wave wrote all rows (quads 0..3); no barrier needed
    float cq[8], sq[8];
#pragma unroll
    for (int q = 0; q < 8; q++) {
        cq[q] = cs[gw][m][q * 2];
        sq[q] = cs[gw][m][q * 2 + 1];
    }

    // ---- build product-state A-fragments (amp bits: j->q012, quad->q34, kk->q567)
    float t01[4] = {cq[0]*cq[1], sq[0]*cq[1], cq[0]*sq[1], sq[0]*sq[1]};
    float plow[8];
#pragma unroll
    for (int j = 0; j < 8; j++) plow[j] = t01[j & 3] * ((j & 4) ? sq[2] : cq[2]);
    float pqd = ((quad & 1) ? sq[3] : cq[3]) * ((quad & 2) ? sq[4] : cq[4]);
    float t56[4] = {cq[5]*cq[6], sq[5]*cq[6], cq[5]*sq[6], sq[5]*sq[6]};
    float phi[8];
#pragma unroll
    for (int kk = 0; kk < 8; kk++)
        phi[kk] = t56[kk & 3] * ((kk & 4) ? sq[7] : cq[7]) * pqd;
    v8h aenc[8];
#pragma unroll
    for (int kk = 0; kk < 8; kk++)
#pragma unroll
        for (int j = 0; j < 8; j++)
            aenc[kk][j] = (_Float16)(plow[j] * phi[kk]);

    // ---- PSI GEMM + |psi|^2 * T head (HW-verified R3 structure) -----------
    float oacc[4][NCLS] = {};
#pragma unroll
    for (int t = 0; t < 16; t++) {
        int col = t * 16 + m;
        float tc[NCLS];
#pragma unroll
        for (int c = 0; c < NCLS; c++) tc[c] = Tl[col * NCLS + c];

        v4f ar = {0.f, 0.f, 0.f, 0.f}, ai = {0.f, 0.f, 0.f, 0.f};
#pragma unroll
        for (int kk = 0; kk < 8; kk++) {
            size_t fb = ((size_t)(t * 8 + kk)) * 512 + (size_t)lane * 8;
            v8h br = *(const v8h*)(Bre + fb);
            v8h bi = *(const v8h*)(Bim + fb);
            ar = __builtin_amdgcn_mfma_f32_16x16x32_f16(aenc[kk], br, ar, 0, 0, 0);
            ai = __builtin_amdgcn_mfma_f32_16x16x32_f16(aenc[kk], bi, ai, 0, 0, 0);
        }
#pragma unroll
        for (int r = 0; r < 4; r++) {
            float pv = ar[r] * ar[r] + ai[r] * ai[r];
#pragma unroll
            for (int c = 0; c < NCLS; c++)
                oacc[r][c] = fmaf(pv, tc[c], oacc[r][c]);
        }
    }
#pragma unroll
    for (int r = 0; r < 4; r++) {
#pragma unroll
        for (int c = 0; c < NCLS; c++) {
            float v = oacc[r][c];
            v += dpp_term<0x111, 0xf>(v);
            v += dpp_term<0x112, 0xf>(v);
            v += dpp_term<0x114, 0xf>(v);
            v += dpp_term<0x118, 0xf>(v);
            oacc[r][c] = v; // lane 15 of each 16-group = col sum
        }
    }
    if (m == 15) {
#pragma unroll
        for (int r = 0; r < 4; r++) {
            int row = rowbase + quad * 4 + r;
#pragma unroll
            for (int c = 0; c < NCLS; c++)
                out[row * NCLS + c] = oacc[r][c] + out_b[c];
        }
    }
}

extern "C" void kernel_launch(void* const* d_in, const int* in_sizes, int n_in,
                              void* d_out, int out_size, void* d_ws, size_t ws_size,
                              hipStream_t stream) {
    const float* x      = (const float*)d_in[0];
    const float* proj_w = (const float*)d_in[1];
    const float* qnn_w  = (const float*)d_in[2];
    const float* out_w  = (const float*)d_in[3];
    const float* out_b  = (const float*)d_in[4];
    float* out = (float*)d_out;

    char* ws = (char*)d_ws;
    float*    T   = (float*)(ws + 0);
    _Float16* PB  = (_Float16*)(ws + 16384);
    _Float16* Bre = (_Float16*)(ws + 32768);
    _Float16* Bim = (_Float16*)(ws + 163840);

    build_all<<<256, 64, 0, stream>>>(qnn_w, proj_w, out_w, T, PB, Bre, Bim);
    enc_gemm_head<<<NBATCH / 32, 128, 0, stream>>>(x, PB, Bre, Bim, T, out_b, out);
}

// Round 5
// 108.414 us; speedup vs baseline: 1.0649x; 1.0649x over previous
//
#include <hip/hip_runtime.h>
#include <math.h>

#define NQ 8
#define NDEPTH 3
#define FEAT 512
#define NCLS 10
#define NBATCH 8192

typedef _Float16 v8h __attribute__((ext_vector_type(8)));
typedef float v4f __attribute__((ext_vector_type(4)));

// ---------------------------------------------------------------------------
// Workspace layout:
//   T:   256*10 f32 @ 0       (10240 B)
//   PB:  16*512 f16 @ 16384   (16384 B)  proj_w rows 0..7, zero-padded 8..15
//   Bre: 256*256 f16 @ 32768  (131072 B) circuit unitary, MFMA-B packed
//   Bim: 256*256 f16 @ 163840 (131072 B)
// ---------------------------------------------------------------------------

// ---------------------------------------------------------------------------
// DPP helpers (HW-verified R2/R3/R4)
// ---------------------------------------------------------------------------
template <int CTRL, int ROW_MASK>
__device__ __forceinline__ float dpp_term(float v) {
    return __int_as_float(__builtin_amdgcn_update_dpp(
        0, __float_as_int(v), CTRL, ROW_MASK, 0xf, true));
}

template <int CTRL>
__device__ __forceinline__ float dpp_xor(float v) {
    return __int_as_float(__builtin_amdgcn_update_dpp(
        0, __float_as_int(v), CTRL, 0xf, 0xf, true));
}

__device__ __forceinline__ float fast_tanh(float v) {
    float e = __expf(2.f * v);
    return 1.f - 2.f / (e + 1.f);
}

// ---------------------------------------------------------------------------
// Gate application (HW-verified R2/R3/R4). State: amp index = lane*4 + j.
// ---------------------------------------------------------------------------
__device__ __forceinline__ void cgate_pair(const float* __restrict__ u,
        float& r0, float& i0, float& r1, float& i1) {
    float nr0 = u[0]*r0 - u[1]*i0 + u[2]*r1 - u[3]*i1;
    float ni0 = u[0]*i0 + u[1]*r0 + u[2]*i1 + u[3]*r1;
    float nr1 = u[4]*r0 - u[5]*i0 + u[6]*r1 - u[7]*i1;
    float ni1 = u[4]*i0 + u[5]*r0 + u[6]*i1 + u[7]*r1;
    r0 = nr0; i0 = ni0; r1 = nr1; i1 = ni1;
}

__device__ __forceinline__ void cgate_shfl(const float* __restrict__ u, int bit,
        int mask, float (&re)[4], float (&im)[4]) {
    float dr  = bit ? u[6] : u[0], di = bit ? u[7] : u[1];
    float orr = bit ? u[4] : u[2], oi = bit ? u[5] : u[3];
#pragma unroll
    for (int j = 0; j < 4; j++) {
        float pr = __shfl_xor(re[j], mask);
        float pi = __shfl_xor(im[j], mask);
        float nr = dr*re[j] - di*im[j] + orr*pr - oi*pi;
        float ni = dr*im[j] + di*re[j] + orr*pi + oi*pr;
        re[j] = nr; im[j] = ni;
    }
}

template <int CTRL>
__device__ __forceinline__ void cgate_dpp(const float* __restrict__ u, int bit,
        float (&re)[4], float (&im)[4]) {
    float dr  = bit ? u[6] : u[0], di = bit ? u[7] : u[1];
    float orr = bit ? u[4] : u[2], oi = bit ? u[5] : u[3];
#pragma unroll
    for (int j = 0; j < 4; j++) {
        float pr = dpp_xor<CTRL>(re[j]);
        float pi = dpp_xor<CTRL>(im[j]);
        float nr = dr*re[j] - di*im[j] + orr*pr - oi*pi;
        float ni = dr*im[j] + di*re[j] + orr*pi + oi*pr;
        re[j] = nr; im[j] = ni;
    }
}

__device__ __forceinline__ void apply_circuit(const float* __restrict__ gates,
        int lane, float (&re)[4], float (&im)[4]) {
#pragma unroll
    for (int l = 0; l < NDEPTH; l++) {
        const float* g = gates + l * NQ * 8;
        cgate_pair(g, re[0], im[0], re[1], im[1]);
        cgate_pair(g, re[2], im[2], re[3], im[3]);
        cgate_pair(g + 8,  re[0], im[0], re[2], im[2]);
        cgate_pair(g + 8,  re[1], im[1], re[3], im[3]);
        cgate_dpp<0xB1>(g + 16, lane & 1,        re, im);
        cgate_dpp<0x4E>(g + 24, (lane >> 1) & 1, re, im);
        cgate_shfl(g + 32, (lane >> 2) & 1, 4,  re, im);
        cgate_shfl(g + 40, (lane >> 3) & 1, 8,  re, im);
        cgate_shfl(g + 48, (lane >> 4) & 1, 16, re, im);
        cgate_shfl(g + 56, (lane >> 5) & 1, 32, re, im);
        { float t = re[1]; re[1] = re[3]; re[3] = t;
          t = im[1]; im[1] = im[3]; im[3] = t; }
        int base  = lane ^ ((lane << 1) & 63);
        int base2 = base ^ 1;
        re[0] = __shfl(re[0], base);  im[0] = __shfl(im[0], base);
        re[1] = __shfl(re[1], base);  im[1] = __shfl(im[1], base);
        re[2] = __shfl(re[2], base2); im[2] = __shfl(im[2], base2);
        re[3] = __shfl(re[3], base2); im[3] = __shfl(im[3], base2);
        int bit5 = (lane >> 5) & 1;
        {
            float t0 = bit5 ? re[1] : re[0], t1 = bit5 ? re[0] : re[1];
            float t2 = bit5 ? re[3] : re[2], t3 = bit5 ? re[2] : re[3];
            re[0] = t0; re[1] = t1; re[2] = t2; re[3] = t3;
            t0 = bit5 ? im[1] : im[0]; t1 = bit5 ? im[0] : im[1];
            t2 = bit5 ? im[3] : im[2]; t3 = bit5 ? im[2] : im[3];
            im[0] = t0; im[1] = t1; im[2] = t2; im[3] = t3;
        }
    }
}

// ---------------------------------------------------------------------------
// k1: one block per basis column p (HW-verified R4). Block 0 also writes
// T and the f16-padded proj_w (PB).
// ---------------------------------------------------------------------------
__global__ __launch_bounds__(64) void build_all(
        const float* __restrict__ qnn_w, const float* __restrict__ proj_w,
        const float* __restrict__ out_w,
        float* __restrict__ T, _Float16* __restrict__ PB,
        _Float16* __restrict__ Bre, _Float16* __restrict__ Bim) {
    __shared__ float gl[NDEPTH * NQ * 8];
    int tid = threadIdx.x;
    if (tid < NDEPTH * NQ) {
        float t0 = 0.5f * qnn_w[tid * 3 + 0];
        float t1 = 0.5f * qnn_w[tid * 3 + 1];
        float t2 = 0.5f * qnn_w[tid * 3 + 2];
        float c0 = cosf(t0), s0 = sinf(t0);
        float c1 = cosf(t1), s1 = sinf(t1);
        float c2 = cosf(t2), s2 = sinf(t2);
        float m00r =  c1 * c0, m00i =  s1 * s0;
        float m01r = -s1 * c0, m01i = -c1 * s0;
        float m10r =  s1 * c0, m10i = -c1 * s0;
        float m11r =  c1 * c0, m11i = -s1 * s0;
        float* g = gl + tid * 8;
        g[0] =  c2 * m00r + s2 * m10i;  g[1] =  c2 * m00i - s2 * m10r;
        g[2] =  c2 * m01r + s2 * m11i;  g[3] =  c2 * m01i - s2 * m11r;
        g[4] =  s2 * m00i + c2 * m10r;  g[5] = -s2 * m00r + c2 * m10i;
        g[6] =  s2 * m01i + c2 * m11r;  g[7] = -s2 * m01r + c2 * m11i;
    }
    if (blockIdx.x == 0) {
        for (int i = tid; i < 256; i += 64) {
#pragma unroll
            for (int c = 0; c < NCLS; c++) {
                float s = 0.f;
#pragma unroll
                for (int q = 0; q < NQ; q++)
                    s += (((i >> q) & 1) ? -1.f : 1.f) * out_w[c * NQ + q];
                T[i * NCLS + c] = s;
            }
        }
        for (int e = 0; e < 128; e++) {
            int idx = e * 64 + tid;
            int n = idx >> 9, k = idx & 511;
            PB[idx] = (n < 8) ? (_Float16)proj_w[n * FEAT + k] : (_Float16)0.f;
        }
    }
    __syncthreads();

    int lane = tid;
    int p = blockIdx.x;
    float re[4], im[4];
#pragma unroll
    for (int j = 0; j < 4; j++) {
        re[j] = (lane * 4 + j == p) ? 1.f : 0.f;
        im[j] = 0.f;
    }
    apply_circuit(gl, lane, re, im);

    int t  = lane >> 2;
    int kk = p >> 5;
    int qp = (p >> 3) & 3;
    int j  = p & 7;
#pragma unroll
    for (int r = 0; r < 4; r++) {
        int n15  = (lane & 3) * 4 + r;
        int flat = ((t * 8 + kk) * 64 + qp * 16 + n15) * 8 + j;
        Bre[flat] = (_Float16)re[r];
        Bim[flat] = (_Float16)im[r];
    }
}

// ---------------------------------------------------------------------------
// k2: fused encoding-dots (MFMA) + product-state build + PSI GEMM + head.
// 512 blocks x 256 threads. All 4 waves of a block share the SAME 16 batch
// rows; wave w handles column tiles t in [4w, 4w+4). Partial T-weighted
// sums are combined through LDS (column sum is linear -> exact).
// ---------------------------------------------------------------------------
__global__ __launch_bounds__(256) void enc_gemm_head(
        const float* __restrict__ x, const _Float16* __restrict__ PB,
        const _Float16* __restrict__ Bre, const _Float16* __restrict__ Bim,
        const float* __restrict__ T, const float* __restrict__ out_b,
        float* __restrict__ out) {
    __shared__ float Tl[256 * NCLS];
    __shared__ float cs[4][16][16];       // [wave][row][q*2 + (0=c,1=s)]
    __shared__ float part[4][16][NCLS];   // per-wave partial outputs

    int tid = threadIdx.x;
    for (int e = 0; e < 10; e++) Tl[e * 256 + tid] = T[e * 256 + tid];
    __syncthreads();

    int lane = tid & 63;
    int gw   = tid >> 6;              // wave id 0..3 = column-tile group
    int m    = lane & 15, quad = lane >> 4;
    int rowbase = blockIdx.x * 16;    // same 16 rows for all 4 waves

    // ---- encoding dots via MFMA: D[row][q] = x[row]·proj_w[q] -------------
    // (redundant across the 4 waves; x is L1-hot after the first)
    const float* xrow = x + (size_t)(rowbase + m) * FEAT;
    v4f dacc = {0.f, 0.f, 0.f, 0.f};
#pragma unroll
    for (int kk = 0; kk < 16; kk++) {
        int k0 = kk * 32 + quad * 8;
        float4 xa = *(const float4*)(xrow + k0);
        float4 xb = *(const float4*)(xrow + k0 + 4);
        v8h av;
        av[0] = (_Float16)xa.x; av[1] = (_Float16)xa.y;
        av[2] = (_Float16)xa.z; av[3] = (_Float16)xa.w;
        av[4] = (_Float16)xb.x; av[5] = (_Float16)xb.y;
        av[6] = (_Float16)xb.z; av[7] = (_Float16)xb.w;
        v8h bv = *(const v8h*)(PB + m * FEAT + k0);
        dacc = __builtin_amdgcn_mfma_f32_16x16x32_f16(av, bv, dacc, 0, 0, 0);
    }
    // lane holds D[row = rowbase+quad*4+r][q = m] (C-layout, verified)
#pragma unroll
    for (int r = 0; r < 4; r++) {
        float th = fast_tanh(dacc[r]) * 0.78539816339744830962f; // half-angle
        float sv = __sinf(th), cv = __cosf(th);
        if (m < 8) {
            cs[gw][quad * 4 + r][m * 2]     = cv;
            cs[gw][quad * 4 + r][m * 2 + 1] = sv;
        }
    }
    // wave-local LDS round-trip (same wave wrote all 16 rows; no barrier)
    float cq[8], sq[8];
#pragma unroll
    for (int q = 0; q < 8; q++) {
        cq[q] = cs[gw][m][q * 2];
        sq[q] = cs[gw][m][q * 2 + 1];
    }

    // ---- product-state A-fragments (amp bits: j->q012, quad->q34, kk->q567)
    float t01[4] = {cq[0]*cq[1], sq[0]*cq[1], cq[0]*sq[1], sq[0]*sq[1]};
    float plow[8];
#pragma unroll
    for (int j = 0; j < 8; j++) plow[j] = t01[j & 3] * ((j & 4) ? sq[2] : cq[2]);
    float pqd = ((quad & 1) ? sq[3] : cq[3]) * ((quad & 2) ? sq[4] : cq[4]);
    float t56[4] = {cq[5]*cq[6], sq[5]*cq[6], cq[5]*sq[6], sq[5]*sq[6]};
    float phi[8];
#pragma unroll
    for (int kk = 0; kk < 8; kk++)
        phi[kk] = t56[kk & 3] * ((kk & 4) ? sq[7] : cq[7]) * pqd;
    v8h aenc[8];
#pragma unroll
    for (int kk = 0; kk < 8; kk++)
#pragma unroll
        for (int j = 0; j < 8; j++)
            aenc[kk][j] = (_Float16)(plow[j] * phi[kk]);

    // ---- PSI GEMM + |psi|^2 * T partial head (verified structure) ---------
    float oacc[4][NCLS] = {};
#pragma unroll
    for (int tt = 0; tt < 4; tt++) {
        int t = gw * 4 + tt;
        int col = t * 16 + m;
        float tc[NCLS];
#pragma unroll
        for (int c = 0; c < NCLS; c++) tc[c] = Tl[col * NCLS + c];

        v4f ar = {0.f, 0.f, 0.f, 0.f}, ai = {0.f, 0.f, 0.f, 0.f};
#pragma unroll
        for (int kk = 0; kk < 8; kk++) {
            size_t fb = ((size_t)(t * 8 + kk)) * 512 + (size_t)lane * 8;
            v8h br = *(const v8h*)(Bre + fb);
            v8h bi = *(const v8h*)(Bim + fb);
            ar = __builtin_amdgcn_mfma_f32_16x16x32_f16(aenc[kk], br, ar, 0, 0, 0);
            ai = __builtin_amdgcn_mfma_f32_16x16x32_f16(aenc[kk], bi, ai, 0, 0, 0);
        }
#pragma unroll
        for (int r = 0; r < 4; r++) {
            float pv = ar[r] * ar[r] + ai[r] * ai[r];
#pragma unroll
            for (int c = 0; c < NCLS; c++)
                oacc[r][c] = fmaf(pv, tc[c], oacc[r][c]);
        }
    }
    // reduce over the 16 lanes of each quad group (cols within the wave)
#pragma unroll
    for (int r = 0; r < 4; r++) {
#pragma unroll
        for (int c = 0; c < NCLS; c++) {
            float v = oacc[r][c];
            v += dpp_term<0x111, 0xf>(v);
            v += dpp_term<0x112, 0xf>(v);
            v += dpp_term<0x114, 0xf>(v);
            v += dpp_term<0x118, 0xf>(v);
            oacc[r][c] = v; // lane m==15 of each group = partial col sum
        }
    }
    if (m == 15) {
#pragma unroll
        for (int r = 0; r < 4; r++)
#pragma unroll
            for (int c = 0; c < NCLS; c++)
                part[gw][quad * 4 + r][c] = oacc[r][c];
    }
    __syncthreads();
    // combine the 4 waves' column partials and write out
    if (tid < 16 * NCLS) {
        int row = tid / NCLS, c = tid % NCLS;
        float v = part[0][row][c] + part[1][row][c]
                + part[2][row][c] + part[3][row][c] + out_b[c];
        out[(size_t)(rowbase + row) * NCLS + c] = v;
    }
}

extern "C" void kernel_launch(void* const* d_in, const int* in_sizes, int n_in,
                              void* d_out, int out_size, void* d_ws, size_t ws_size,
                              hipStream_t stream) {
    const float* x      = (const float*)d_in[0];
    const float* proj_w = (const float*)d_in[1];
    const float* qnn_w  = (const float*)d_in[2];
    const float* out_w  = (const float*)d_in[3];
    const float* out_b  = (const float*)d_in[4];
    float* out = (float*)d_out;

    char* ws = (char*)d_ws;
    float*    T   = (float*)(ws + 0);
    _Float16* PB  = (_Float16*)(ws + 16384);
    _Float16* Bre = (_Float16*)(ws + 32768);
    _Float16* Bim = (_Float16*)(ws + 163840);

    build_all<<<256, 64, 0, stream>>>(qnn_w, proj_w, out_w, T, PB, Bre, Bim);
    enc_gemm_head<<<NBATCH / 16, 256, 0, stream>>>(x, PB, Bre, Bim, T, out_b, out);
}

// Round 6
// 95.775 us; speedup vs baseline: 1.2055x; 1.1320x over previous
//
#include <hip/hip_runtime.h>
#include <math.h>

#define NQ 8
#define NDEPTH 3
#define FEAT 512
#define NCLS 10
#define NBATCH 8192

typedef _Float16 v8h __attribute__((ext_vector_type(8)));
typedef float v4f __attribute__((ext_vector_type(4)));

// ---------------------------------------------------------------------------
// Workspace layout:
//   T:   256*10 f32 @ 0       (10240 B)
//   PB:  16*512 f16 @ 16384   (16384 B)  proj_w rows 0..7, zero-padded 8..15
//   Bre: 256*256 f16 @ 32768  (131072 B) circuit unitary, MFMA-B packed
//   Bim: 256*256 f16 @ 163840 (131072 B)
// ---------------------------------------------------------------------------

// ---------------------------------------------------------------------------
// DPP helpers (HW-verified R2..R5)
// ---------------------------------------------------------------------------
template <int CTRL, int ROW_MASK>
__device__ __forceinline__ float dpp_term(float v) {
    return __int_as_float(__builtin_amdgcn_update_dpp(
        0, __float_as_int(v), CTRL, ROW_MASK, 0xf, true));
}

template <int CTRL>
__device__ __forceinline__ float dpp_xor(float v) {
    return __int_as_float(__builtin_amdgcn_update_dpp(
        0, __float_as_int(v), CTRL, 0xf, 0xf, true));
}

__device__ __forceinline__ float fast_tanh(float v) {
    float e = __expf(2.f * v);
    return 1.f - 2.f / (e + 1.f);
}

// ---------------------------------------------------------------------------
// Gate application (HW-verified R2..R5). State: amp index = lane*4 + j.
// ---------------------------------------------------------------------------
__device__ __forceinline__ void cgate_pair(const float* __restrict__ u,
        float& r0, float& i0, float& r1, float& i1) {
    float nr0 = u[0]*r0 - u[1]*i0 + u[2]*r1 - u[3]*i1;
    float ni0 = u[0]*i0 + u[1]*r0 + u[2]*i1 + u[3]*r1;
    float nr1 = u[4]*r0 - u[5]*i0 + u[6]*r1 - u[7]*i1;
    float ni1 = u[4]*i0 + u[5]*r0 + u[6]*i1 + u[7]*r1;
    r0 = nr0; i0 = ni0; r1 = nr1; i1 = ni1;
}

__device__ __forceinline__ void cgate_shfl(const float* __restrict__ u, int bit,
        int mask, float (&re)[4], float (&im)[4]) {
    float dr  = bit ? u[6] : u[0], di = bit ? u[7] : u[1];
    float orr = bit ? u[4] : u[2], oi = bit ? u[5] : u[3];
#pragma unroll
    for (int j = 0; j < 4; j++) {
        float pr = __shfl_xor(re[j], mask);
        float pi = __shfl_xor(im[j], mask);
        float nr = dr*re[j] - di*im[j] + orr*pr - oi*pi;
        float ni = dr*im[j] + di*re[j] + orr*pi + oi*pr;
        re[j] = nr; im[j] = ni;
    }
}

template <int CTRL>
__device__ __forceinline__ void cgate_dpp(const float* __restrict__ u, int bit,
        float (&re)[4], float (&im)[4]) {
    float dr  = bit ? u[6] : u[0], di = bit ? u[7] : u[1];
    float orr = bit ? u[4] : u[2], oi = bit ? u[5] : u[3];
#pragma unroll
    for (int j = 0; j < 4; j++) {
        float pr = dpp_xor<CTRL>(re[j]);
        float pi = dpp_xor<CTRL>(im[j]);
        float nr = dr*re[j] - di*im[j] + orr*pr - oi*pi;
        float ni = dr*im[j] + di*re[j] + orr*pi + oi*pr;
        re[j] = nr; im[j] = ni;
    }
}

__device__ __forceinline__ void apply_circuit(const float* __restrict__ gates,
        int lane, float (&re)[4], float (&im)[4]) {
#pragma unroll
    for (int l = 0; l < NDEPTH; l++) {
        const float* g = gates + l * NQ * 8;
        cgate_pair(g, re[0], im[0], re[1], im[1]);
        cgate_pair(g, re[2], im[2], re[3], im[3]);
        cgate_pair(g + 8,  re[0], im[0], re[2], im[2]);
        cgate_pair(g + 8,  re[1], im[1], re[3], im[3]);
        cgate_dpp<0xB1>(g + 16, lane & 1,        re, im);
        cgate_dpp<0x4E>(g + 24, (lane >> 1) & 1, re, im);
        cgate_shfl(g + 32, (lane >> 2) & 1, 4,  re, im);
        cgate_shfl(g + 40, (lane >> 3) & 1, 8,  re, im);
        cgate_shfl(g + 48, (lane >> 4) & 1, 16, re, im);
        cgate_shfl(g + 56, (lane >> 5) & 1, 32, re, im);
        { float t = re[1]; re[1] = re[3]; re[3] = t;
          t = im[1]; im[1] = im[3]; im[3] = t; }
        int base  = lane ^ ((lane << 1) & 63);
        int base2 = base ^ 1;
        re[0] = __shfl(re[0], base);  im[0] = __shfl(im[0], base);
        re[1] = __shfl(re[1], base);  im[1] = __shfl(im[1], base);
        re[2] = __shfl(re[2], base2); im[2] = __shfl(im[2], base2);
        re[3] = __shfl(re[3], base2); im[3] = __shfl(im[3], base2);
        int bit5 = (lane >> 5) & 1;
        {
            float t0 = bit5 ? re[1] : re[0], t1 = bit5 ? re[0] : re[1];
            float t2 = bit5 ? re[3] : re[2], t3 = bit5 ? re[2] : re[3];
            re[0] = t0; re[1] = t1; re[2] = t2; re[3] = t3;
            t0 = bit5 ? im[1] : im[0]; t1 = bit5 ? im[0] : im[1];
            t2 = bit5 ? im[3] : im[2]; t3 = bit5 ? im[2] : im[3];
            im[0] = t0; im[1] = t1; im[2] = t2; im[3] = t3;
        }
    }
}

// ---------------------------------------------------------------------------
// k1: one block per basis column p. PB and T writes are DISTRIBUTED across
// blocks (R5 had block 0 doing 128 serial PB iterations -> straggler).
// ---------------------------------------------------------------------------
__global__ __launch_bounds__(64) void build_all(
        const float* __restrict__ qnn_w, const float* __restrict__ proj_w,
        const float* __restrict__ out_w,
        float* __restrict__ T, _Float16* __restrict__ PB,
        _Float16* __restrict__ Bre, _Float16* __restrict__ Bim) {
    __shared__ float gl[NDEPTH * NQ * 8];
    int tid = threadIdx.x;
    int p = blockIdx.x;
    if (tid < NDEPTH * NQ) {
        float t0 = 0.5f * qnn_w[tid * 3 + 0];
        float t1 = 0.5f * qnn_w[tid * 3 + 1];
        float t2 = 0.5f * qnn_w[tid * 3 + 2];
        float c0 = cosf(t0), s0 = sinf(t0);
        float c1 = cosf(t1), s1 = sinf(t1);
        float c2 = cosf(t2), s2 = sinf(t2);
        float m00r =  c1 * c0, m00i =  s1 * s0;
        float m01r = -s1 * c0, m01i = -c1 * s0;
        float m10r =  s1 * c0, m10i = -c1 * s0;
        float m11r =  c1 * c0, m11i = -s1 * s0;
        float* g = gl + tid * 8;
        g[0] =  c2 * m00r + s2 * m10i;  g[1] =  c2 * m00i - s2 * m10r;
        g[2] =  c2 * m01r + s2 * m11i;  g[3] =  c2 * m01i - s2 * m11r;
        g[4] =  s2 * m00i + c2 * m10r;  g[5] = -s2 * m00r + c2 * m10i;
        g[6] =  s2 * m01i + c2 * m11r;  g[7] = -s2 * m01r + c2 * m11i;
    }
    // distributed PB: blocks 0..127, 64 elements each
    if (p < 128) {
        int idx = p * 64 + tid;
        int n = idx >> 9, k = idx & 511;
        PB[idx] = (n < 8) ? (_Float16)proj_w[n * FEAT + k] : (_Float16)0.f;
    } else if (p < 192) {
        // distributed T: blocks 128..191, 4 rows each
        int i = (p - 128) * 4 + (tid >> 4);
        int c = tid & 15;
        if (c < NCLS) {
            float s = 0.f;
#pragma unroll
            for (int q = 0; q < NQ; q++)
                s += (((i >> q) & 1) ? -1.f : 1.f) * out_w[c * NQ + q];
            T[i * NCLS + c] = s;
        }
    }
    __syncthreads();

    int lane = tid;
    float re[4], im[4];
#pragma unroll
    for (int j = 0; j < 4; j++) {
        re[j] = (lane * 4 + j == p) ? 1.f : 0.f;
        im[j] = 0.f;
    }
    apply_circuit(gl, lane, re, im);

    // scatter into MFMA-B fragment layout (HW-verified R3..R5)
    int t  = lane >> 2;
    int kk = p >> 5;
    int qp = (p >> 3) & 3;
    int j  = p & 7;
#pragma unroll
    for (int r = 0; r < 4; r++) {
        int n15  = (lane & 3) * 4 + r;
        int flat = ((t * 8 + kk) * 64 + qp * 16 + n15) * 8 + j;
        Bre[flat] = (_Float16)re[r];
        Bim[flat] = (_Float16)im[r];
    }
}

// ---------------------------------------------------------------------------
// k2: fused encoding-dots (MFMA) + product-state build + PSI GEMM + head.
// 512 blocks x 256 threads; waves share 16 rows, wave gw owns tiles
// [4gw, 4gw+4). UNROLL-CAPPED loops to avoid VGPR spill (R4/R5 pathology).
// ---------------------------------------------------------------------------
__global__ __launch_bounds__(256, 2) void enc_gemm_head(
        const float* __restrict__ x, const _Float16* __restrict__ PB,
        const _Float16* __restrict__ Bre, const _Float16* __restrict__ Bim,
        const float* __restrict__ T, const float* __restrict__ out_b,
        float* __restrict__ out) {
    __shared__ float Tl[256 * NCLS];
    __shared__ float cs[4][16][16];       // [wave][row][q*2 + (0=c,1=s)]
    __shared__ float part[4][16][NCLS];   // per-wave partial outputs

    int tid = threadIdx.x;
#pragma unroll
    for (int e = 0; e < 10; e++) Tl[e * 256 + tid] = T[e * 256 + tid];
    __syncthreads();

    int lane = tid & 63;
    int gw   = tid >> 6;
    int m    = lane & 15, quad = lane >> 4;
    int rowbase = blockIdx.x * 16;

    // ---- encoding dots via MFMA: D[row][q] = x[row]·proj_w[q] -------------
    const float* xrow = x + (size_t)(rowbase + m) * FEAT;
    v4f dacc = {0.f, 0.f, 0.f, 0.f};
#pragma unroll 2                      // cap in-flight loads (spill control)
    for (int kk = 0; kk < 16; kk++) {
        int k0 = kk * 32 + quad * 8;
        float4 xa = *(const float4*)(xrow + k0);
        float4 xb = *(const float4*)(xrow + k0 + 4);
        v8h av;
        av[0] = (_Float16)xa.x; av[1] = (_Float16)xa.y;
        av[2] = (_Float16)xa.z; av[3] = (_Float16)xa.w;
        av[4] = (_Float16)xb.x; av[5] = (_Float16)xb.y;
        av[6] = (_Float16)xb.z; av[7] = (_Float16)xb.w;
        v8h bv = *(const v8h*)(PB + m * FEAT + k0);
        dacc = __builtin_amdgcn_mfma_f32_16x16x32_f16(av, bv, dacc, 0, 0, 0);
    }
#pragma unroll
    for (int r = 0; r < 4; r++) {
        float th = fast_tanh(dacc[r]) * 0.78539816339744830962f; // half-angle
        float sv = __sinf(th), cv = __cosf(th);
        if (m < 8) {
            cs[gw][quad * 4 + r][m * 2]     = cv;
            cs[gw][quad * 4 + r][m * 2 + 1] = sv;
        }
    }
    float cq[8], sq[8];
#pragma unroll
    for (int q = 0; q < 8; q++) {
        cq[q] = cs[gw][m][q * 2];
        sq[q] = cs[gw][m][q * 2 + 1];
    }

    // ---- product-state A-fragments (amp bits: j->q012, quad->q34, kk->q567)
    float t01[4] = {cq[0]*cq[1], sq[0]*cq[1], cq[0]*sq[1], sq[0]*sq[1]};
    float plow[8];
#pragma unroll
    for (int j = 0; j < 8; j++) plow[j] = t01[j & 3] * ((j & 4) ? sq[2] : cq[2]);
    float pqd = ((quad & 1) ? sq[3] : cq[3]) * ((quad & 2) ? sq[4] : cq[4]);
    float t56[4] = {cq[5]*cq[6], sq[5]*cq[6], cq[5]*sq[6], sq[5]*sq[6]};
    float phi[8];
#pragma unroll
    for (int kk = 0; kk < 8; kk++)
        phi[kk] = t56[kk & 3] * ((kk & 4) ? sq[7] : cq[7]) * pqd;
    v8h aenc[8];
#pragma unroll
    for (int kk = 0; kk < 8; kk++)
#pragma unroll
        for (int j = 0; j < 8; j++)
            aenc[kk][j] = (_Float16)(plow[j] * phi[kk]);

    // ---- PSI GEMM + |psi|^2 * T partial head -------------------------------
    float oacc[4][NCLS] = {};
#pragma unroll 1                      // keep per-iter load footprint bounded
    for (int tt = 0; tt < 4; tt++) {
        int t = gw * 4 + tt;
        int col = t * 16 + m;
        float tc[NCLS];
#pragma unroll
        for (int c = 0; c < NCLS; c++) tc[c] = Tl[col * NCLS + c];

        v4f ar = {0.f, 0.f, 0.f, 0.f}, ai = {0.f, 0.f, 0.f, 0.f};
#pragma unroll
        for (int kk = 0; kk < 8; kk++) {
            size_t fb = ((size_t)(t * 8 + kk)) * 512 + (size_t)lane * 8;
            v8h br = *(const v8h*)(Bre + fb);
            v8h bi = *(const v8h*)(Bim + fb);
            ar = __builtin_amdgcn_mfma_f32_16x16x32_f16(aenc[kk], br, ar, 0, 0, 0);
            ai = __builtin_amdgcn_mfma_f32_16x16x32_f16(aenc[kk], bi, ai, 0, 0, 0);
        }
#pragma unroll
        for (int r = 0; r < 4; r++) {
            float pv = ar[r] * ar[r] + ai[r] * ai[r];
#pragma unroll
            for (int c = 0; c < NCLS; c++)
                oacc[r][c] = fmaf(pv, tc[c], oacc[r][c]);
        }
    }
    // reduce over the 16 lanes of each quad group
#pragma unroll
    for (int r = 0; r < 4; r++) {
#pragma unroll
        for (int c = 0; c < NCLS; c++) {
            float v = oacc[r][c];
            v += dpp_term<0x111, 0xf>(v);
            v += dpp_term<0x112, 0xf>(v);
            v += dpp_term<0x114, 0xf>(v);
            v += dpp_term<0x118, 0xf>(v);
            oacc[r][c] = v;
        }
    }
    if (m == 15) {
#pragma unroll
        for (int r = 0; r < 4; r++)
#pragma unroll
            for (int c = 0; c < NCLS; c++)
                part[gw][quad * 4 + r][c] = oacc[r][c];
    }
    __syncthreads();
    if (tid < 16 * NCLS) {
        int row = tid / NCLS, c = tid % NCLS;
        float v = part[0][row][c] + part[1][row][c]
                + part[2][row][c] + part[3][row][c] + out_b[c];
        out[(size_t)(rowbase + row) * NCLS + c] = v;
    }
}

extern "C" void kernel_launch(void* const* d_in, const int* in_sizes, int n_in,
                              void* d_out, int out_size, void* d_ws, size_t ws_size,
                              hipStream_t stream) {
    const float* x      = (const float*)d_in[0];
    const float* proj_w = (const float*)d_in[1];
    const float* qnn_w  = (const float*)d_in[2];
    const float* out_w  = (const float*)d_in[3];
    const float* out_b  = (const float*)d_in[4];
    float* out = (float*)d_out;

    char* ws = (char*)d_ws;
    float*    T   = (float*)(ws + 0);
    _Float16* PB  = (_Float16*)(ws + 16384);
    _Float16* Bre = (_Float16*)(ws + 32768);
    _Float16* Bim = (_Float16*)(ws + 163840);

    build_all<<<256, 64, 0, stream>>>(qnn_w, proj_w, out_w, T, PB, Bre, Bim);
    enc_gemm_head<<<NBATCH / 16, 256, 0, stream>>>(x, PB, Bre, Bim, T, out_b, out);
}

// Round 7
// 83.673 us; speedup vs baseline: 1.3798x; 1.1446x over previous
//
#include <hip/hip_runtime.h>
#include <math.h>

#define NQ 8
#define NDEPTH 3
#define FEAT 512
#define NCLS 10
#define NBATCH 8192

// ---------------------------------------------------------------------------
// Single fused kernel: R2's HW-verified simulator (85.5 µs run, absmax 3.9e-3)
// with the gate table computed in-block instead of a separate launch.
// State layout: amp index = lane*4 + j ; j = qubits 0,1 ; lane bits = qubits 2..7.
// ---------------------------------------------------------------------------

// DPP helpers (HW-verified R2..R6)
template <int CTRL, int ROW_MASK>
__device__ __forceinline__ float dpp_term(float v) {
    return __int_as_float(__builtin_amdgcn_update_dpp(
        0, __float_as_int(v), CTRL, ROW_MASK, 0xf, true));
}

__device__ __forceinline__ float wave_sum_bcast(float v) {
    v += dpp_term<0x111, 0xf>(v); // row_shr:1
    v += dpp_term<0x112, 0xf>(v); // row_shr:2
    v += dpp_term<0x114, 0xf>(v); // row_shr:4
    v += dpp_term<0x118, 0xf>(v); // row_shr:8
    v += dpp_term<0x142, 0xa>(v); // row_bcast15
    v += dpp_term<0x143, 0xc>(v); // row_bcast31
    return __int_as_float(__builtin_amdgcn_readlane(__float_as_int(v), 63));
}

__device__ __forceinline__ float bcastlane(float v, int srclane) {
    return __int_as_float(__builtin_amdgcn_readlane(__float_as_int(v), srclane));
}

template <int CTRL>
__device__ __forceinline__ float dpp_xor(float v) {
    return __int_as_float(__builtin_amdgcn_update_dpp(
        0, __float_as_int(v), CTRL, 0xf, 0xf, true));
}

__device__ __forceinline__ float fast_tanh(float v) {
    float e = __expf(2.f * v);
    return 1.f - 2.f / (e + 1.f);
}

// Gate application (HW-verified R2)
__device__ __forceinline__ void cgate_pair(const float* __restrict__ u,
        float& r0, float& i0, float& r1, float& i1) {
    float nr0 = u[0]*r0 - u[1]*i0 + u[2]*r1 - u[3]*i1;
    float ni0 = u[0]*i0 + u[1]*r0 + u[2]*i1 + u[3]*r1;
    float nr1 = u[4]*r0 - u[5]*i0 + u[6]*r1 - u[7]*i1;
    float ni1 = u[4]*i0 + u[5]*r0 + u[6]*i1 + u[7]*r1;
    r0 = nr0; i0 = ni0; r1 = nr1; i1 = ni1;
}

__device__ __forceinline__ void cgate_shfl(const float* __restrict__ u, int bit,
        int mask, float (&re)[4], float (&im)[4]) {
    float dr  = bit ? u[6] : u[0], di = bit ? u[7] : u[1];
    float orr = bit ? u[4] : u[2], oi = bit ? u[5] : u[3];
#pragma unroll
    for (int j = 0; j < 4; j++) {
        float pr = __shfl_xor(re[j], mask);
        float pi = __shfl_xor(im[j], mask);
        float nr = dr*re[j] - di*im[j] + orr*pr - oi*pi;
        float ni = dr*im[j] + di*re[j] + orr*pi + oi*pr;
        re[j] = nr; im[j] = ni;
    }
}

template <int CTRL>
__device__ __forceinline__ void cgate_dpp(const float* __restrict__ u, int bit,
        float (&re)[4], float (&im)[4]) {
    float dr  = bit ? u[6] : u[0], di = bit ? u[7] : u[1];
    float orr = bit ? u[4] : u[2], oi = bit ? u[5] : u[3];
#pragma unroll
    for (int j = 0; j < 4; j++) {
        float pr = dpp_xor<CTRL>(re[j]);
        float pi = dpp_xor<CTRL>(im[j]);
        float nr = dr*re[j] - di*im[j] + orr*pr - oi*pi;
        float ni = dr*im[j] + di*re[j] + orr*pi + oi*pr;
        re[j] = nr; im[j] = ni;
    }
}

__global__ __launch_bounds__(256) void qsim_kernel(
        const float* __restrict__ x, const float* __restrict__ proj_w,
        const float* __restrict__ qnn_w, const float* __restrict__ out_w,
        const float* __restrict__ out_b, float* __restrict__ out) {
    __shared__ float gl[NDEPTH * NQ * 8]; // fused RX*RY*RX per (layer,qubit)

    int tid = threadIdx.x;
    // ---- in-block gate table (verified precompute math, R2..R6) -----------
    if (tid < NDEPTH * NQ) {
        float t0 = 0.5f * qnn_w[tid * 3 + 0];
        float t1 = 0.5f * qnn_w[tid * 3 + 1];
        float t2 = 0.5f * qnn_w[tid * 3 + 2];
        float c0 = cosf(t0), s0 = sinf(t0);
        float c1 = cosf(t1), s1 = sinf(t1);
        float c2 = cosf(t2), s2 = sinf(t2);
        // M1 = RY(t1)*RX(t0)
        float m00r =  c1 * c0, m00i =  s1 * s0;
        float m01r = -s1 * c0, m01i = -c1 * s0;
        float m10r =  s1 * c0, m10i = -c1 * s0;
        float m11r =  c1 * c0, m11i = -s1 * s0;
        // U = RX(t2)*M1
        float* g = gl + tid * 8;
        g[0] =  c2 * m00r + s2 * m10i;  g[1] =  c2 * m00i - s2 * m10r;
        g[2] =  c2 * m01r + s2 * m11i;  g[3] =  c2 * m01i - s2 * m11r;
        g[4] =  s2 * m00i + c2 * m10r;  g[5] = -s2 * m00r + c2 * m10i;
        g[6] =  s2 * m01i + c2 * m11r;  g[7] = -s2 * m01r + c2 * m11i;
    }
    __syncthreads();

    int lane = tid & 63;
    int b = blockIdx.x * 4 + (tid >> 6);

    // ---- encoding dots: d[q] = x[b]·proj_w[q] (float4 + DPP reduce) --------
    const float4* xr4 = (const float4*)(x + (size_t)b * FEAT);
    float4 xa = xr4[lane], xb = xr4[lane + 64];
    float dq[8];
#pragma unroll
    for (int q = 0; q < 8; q++) {
        const float4* pw4 = (const float4*)(proj_w + q * FEAT);
        float4 wa = pw4[lane], wb = pw4[lane + 64];
        float acc = xa.x*wa.x + xa.y*wa.y + xa.z*wa.z + xa.w*wa.w
                  + xb.x*wb.x + xb.y*wb.y + xb.z*wb.z + xb.w*wb.w;
        dq[q] = wave_sum_bcast(acc);
    }
    // lane group g = lane>>3 computes sincos of half-angle for qubit g
    int qsel = lane >> 3;
    float a0 = (qsel & 4) ? dq[4] : dq[0];
    float a1 = (qsel & 4) ? dq[5] : dq[1];
    float a2 = (qsel & 4) ? dq[6] : dq[2];
    float a3 = (qsel & 4) ? dq[7] : dq[3];
    float b0 = (qsel & 2) ? a2 : a0;
    float b1 = (qsel & 2) ? a3 : a1;
    float dsel = (qsel & 1) ? b1 : b0;
    float th = fast_tanh(dsel) * 0.78539816339744830962f;
    float se = __sinf(th), ce = __cosf(th);
    float cq[8], sq[8];
#pragma unroll
    for (int q = 0; q < 8; q++) {
        cq[q] = bcastlane(ce, q * 8);
        sq[q] = bcastlane(se, q * 8);
    }

    // ---- encoding layer as product state -----------------------------------
    float F = 1.f;
#pragma unroll
    for (int q = 2; q < 8; q++) {
        int bit = (lane >> (q - 2)) & 1;
        F *= bit ? sq[q] : cq[q];
    }
    float re[4], im[4];
    re[0] = F * cq[0] * cq[1];
    re[1] = F * sq[0] * cq[1];
    re[2] = F * cq[0] * sq[1];
    re[3] = F * sq[0] * sq[1];
    im[0] = im[1] = im[2] = im[3] = 0.f;

    // ---- variational layers (verbatim verified R2) -------------------------
#pragma unroll
    for (int l = 0; l < NDEPTH; l++) {
        const float* g = gl + l * NQ * 8;
        cgate_pair(g, re[0], im[0], re[1], im[1]);
        cgate_pair(g, re[2], im[2], re[3], im[3]);
        cgate_pair(g + 8,  re[0], im[0], re[2], im[2]);
        cgate_pair(g + 8,  re[1], im[1], re[3], im[3]);
        cgate_dpp<0xB1>(g + 16, lane & 1,        re, im);
        cgate_dpp<0x4E>(g + 24, (lane >> 1) & 1, re, im);
        cgate_shfl(g + 32, (lane >> 2) & 1, 4,  re, im);
        cgate_shfl(g + 40, (lane >> 3) & 1, 8,  re, im);
        cgate_shfl(g + 48, (lane >> 4) & 1, 16, re, im);
        cgate_shfl(g + 56, (lane >> 5) & 1, 32, re, im);
        // CNOT ladder
        { float t = re[1]; re[1] = re[3]; re[3] = t;
          t = im[1]; im[1] = im[3]; im[3] = t; }
        int base  = lane ^ ((lane << 1) & 63);
        int base2 = base ^ 1;
        re[0] = __shfl(re[0], base);  im[0] = __shfl(im[0], base);
        re[1] = __shfl(re[1], base);  im[1] = __shfl(im[1], base);
        re[2] = __shfl(re[2], base2); im[2] = __shfl(im[2], base2);
        re[3] = __shfl(re[3], base2); im[3] = __shfl(im[3], base2);
        int bit5 = (lane >> 5) & 1;
        {
            float t0 = bit5 ? re[1] : re[0], t1 = bit5 ? re[0] : re[1];
            float t2 = bit5 ? re[3] : re[2], t3 = bit5 ? re[2] : re[3];
            re[0] = t0; re[1] = t1; re[2] = t2; re[3] = t3;
            t0 = bit5 ? im[1] : im[0]; t1 = bit5 ? im[0] : im[1];
            t2 = bit5 ? im[3] : im[2]; t3 = bit5 ? im[2] : im[3];
            im[0] = t0; im[1] = t1; im[2] = t2; im[3] = t3;
        }
    }

    // ---- PauliZ expectations (DPP reductions, verified R2) -----------------
    float p0 = re[0]*re[0] + im[0]*im[0];
    float p1 = re[1]*re[1] + im[1]*im[1];
    float p2 = re[2]*re[2] + im[2]*im[2];
    float p3 = re[3]*re[3] + im[3]*im[3];
    float pt = p0 + p1 + p2 + p3;
    float eq[8];
    eq[0] = wave_sum_bcast(p0 - p1 + p2 - p3);
    eq[1] = wave_sum_bcast(p0 + p1 - p2 - p3);
#pragma unroll
    for (int q = 2; q < 8; q++) {
        int bit = (lane >> (q - 2)) & 1;
        eq[q] = wave_sum_bcast(bit ? -pt : pt);
    }

    // ---- output head -------------------------------------------------------
    if (lane < NCLS) {
        const float* wrow = out_w + lane * NQ;
        float acc = out_b[lane];
#pragma unroll
        for (int q = 0; q < 8; q++) acc = fmaf(eq[q], wrow[q], acc);
        out[(size_t)b * NCLS + lane] = acc;
    }
}

extern "C" void kernel_launch(void* const* d_in, const int* in_sizes, int n_in,
                              void* d_out, int out_size, void* d_ws, size_t ws_size,
                              hipStream_t stream) {
    const float* x      = (const float*)d_in[0];
    const float* proj_w = (const float*)d_in[1];
    const float* qnn_w  = (const float*)d_in[2];
    const float* out_w  = (const float*)d_in[3];
    const float* out_b  = (const float*)d_in[4];
    float* out = (float*)d_out;

    qsim_kernel<<<NBATCH / 4, 256, 0, stream>>>(x, proj_w, qnn_w, out_w, out_b, out);
}